// Round 1
// baseline (47.660 us; speedup 1.0000x reference)
//
#include <hip/hip_runtime.h>

#define N 384
#define DX 128
#define DZ 32

// norm = 2 / (n*K*(2n-3K-1)) = 2 / (384*5*752)
#define NORM (2.0f / 1443840.0f)
#define KNEI 5.0f
#define TAU_INV 2.0f   // 1/0.5, same for tau_r and tau_s

// D[i][j] = ||A_i - A_j||_2 with the reference's >1e-12 guard.
// One block per row i, one thread per column j.
__global__ void __launch_bounds__(N) dist_kernel(const float* __restrict__ A,
                                                 float* __restrict__ D, int d) {
    __shared__ float rowi[DX];
    const int i = blockIdx.x;
    const int j = threadIdx.x;
    for (int k = threadIdx.x; k < d; k += N) rowi[k] = A[i * d + k];
    __syncthreads();
    const float* __restrict__ aj = A + (long)j * d;
    float sq = 0.f;
    #pragma unroll
    for (int k = 0; k < d; k += 4) {
        float4 v = *reinterpret_cast<const float4*>(aj + k);
        float d0 = v.x - rowi[k + 0];
        float d1 = v.y - rowi[k + 1];
        float d2 = v.z - rowi[k + 2];
        float d3 = v.w - rowi[k + 3];
        sq += d0 * d0 + d1 * d1 + d2 * d2 + d3 * d3;
    }
    D[i * N + j] = (sq > 1e-12f) ? sqrtf(sq) : 0.f;
}

// Per-row fused soft-rank (X) + soft-top-k (Z) + loss contribution.
// sigmoid((d_b - d_a)/tau) = e_b / (e_b + e_a) with e = exp(d/tau).
__global__ void __launch_bounds__(N) loss_kernel(const float* __restrict__ DXm,
                                                 const float* __restrict__ DZm,
                                                 float* __restrict__ partial) {
    __shared__ float ex[N];
    __shared__ float ez[N];
    __shared__ float red[N / 64];
    const int i = blockIdx.x;
    const int a = threadIdx.x;

    ex[a] = __expf(TAU_INV * DXm[i * N + a]);
    ez[a] = __expf(TAU_INV * DZm[i * N + a]);
    __syncthreads();

    const float exa = ex[a];
    const float eza = ez[a];
    float sx = 0.f, sz = 0.f;
    #pragma unroll 8
    for (int b = 0; b < N; ++b) {
        float eb = ex[b];   // wave-uniform address -> LDS broadcast
        float fb = ez[b];
        sx += eb * __builtin_amdgcn_rcpf(eb + exa);
        sz += fb * __builtin_amdgcn_rcpf(fb + eza);
    }

    float soft_rank = 1.f + sx;
    float intr = fmaxf(soft_rank - KNEI, 0.f);
    float R = 1.f + sz;
    float W = fminf(fmaxf((KNEI + 1.f - R) * (1.f / KNEI), 0.f), 1.f);
    float contrib = intr * (1.f - W);

    // wave64 reduce, then cross-wave via LDS
    #pragma unroll
    for (int off = 32; off > 0; off >>= 1)
        contrib += __shfl_down(contrib, off, 64);
    const int lane = a & 63, wid = a >> 6;
    if (lane == 0) red[wid] = contrib;
    __syncthreads();
    if (a == 0) {
        float s = 0.f;
        #pragma unroll
        for (int w = 0; w < N / 64; ++w) s += red[w];
        partial[i] = s;
    }
}

__global__ void __launch_bounds__(N) final_reduce(const float* __restrict__ partial,
                                                  float* __restrict__ out) {
    __shared__ float red[N / 64];
    float v = partial[threadIdx.x];
    #pragma unroll
    for (int off = 32; off > 0; off >>= 1)
        v += __shfl_down(v, off, 64);
    const int lane = threadIdx.x & 63, wid = threadIdx.x >> 6;
    if (lane == 0) red[wid] = v;
    __syncthreads();
    if (threadIdx.x == 0) {
        float s = 0.f;
        #pragma unroll
        for (int w = 0; w < N / 64; ++w) s += red[w];
        out[0] = s * NORM;
    }
}

extern "C" void kernel_launch(void* const* d_in, const int* in_sizes, int n_in,
                              void* d_out, int out_size, void* d_ws, size_t ws_size,
                              hipStream_t stream) {
    const float* X = (const float*)d_in[0];   // (384, 128) f32
    const float* Z = (const float*)d_in[1];   // (384, 32)  f32
    float* out = (float*)d_out;

    float* DXm = (float*)d_ws;                 // N*N f32
    float* DZm = DXm + (size_t)N * N;          // N*N f32
    float* partial = DZm + (size_t)N * N;      // N f32

    dist_kernel<<<N, N, 0, stream>>>(X, DXm, DX);
    dist_kernel<<<N, N, 0, stream>>>(Z, DZm, DZ);
    loss_kernel<<<N, N, 0, stream>>>(DXm, DZm, partial);
    final_reduce<<<1, N, 0, stream>>>(partial, out);
}

// Round 2
// 42.121 us; speedup vs baseline: 1.1315x; 1.1315x over previous
//
#include <hip/hip_runtime.h>

#define N 384
#define DXD 128
#define DZD 32
#define BLK 192          // threads per block (3 waves)
#define NBLK (2 * N)     // 768 blocks = exactly 3 per CU

#define NORM (2.0f / 1443840.0f)   // 2 / (n*K*(2n-3K-1)), n=384, K=5
#define KNEI 5.0f
#define TAU_INV 2.0f               // 1/tau, tau_r == tau_s == 0.5

// Fused: per-row distances (X and Z), exp tables, soft-rank sums, loss.
// Block b handles row i = b>>1 and a-range half (b&1).
// sigmoid((d_b - d_a)/tau) = e_b / (e_b + e_a), e = exp(d/tau).
__global__ void __launch_bounds__(BLK) fused_loss(const float* __restrict__ X,
                                                  const float* __restrict__ Z,
                                                  float* __restrict__ partial) {
    __shared__ float xi[DXD] __attribute__((aligned(16)));
    __shared__ float zi[DZD] __attribute__((aligned(16)));
    __shared__ float ex[N]  __attribute__((aligned(16)));
    __shared__ float ez[N]  __attribute__((aligned(16)));
    __shared__ float red[BLK / 64];

    const int i = blockIdx.x >> 1;
    const int half = blockIdx.x & 1;
    const int t = threadIdx.x;

    // stage row i of X and Z
    for (int k = t; k < DXD; k += BLK) xi[k] = X[i * DXD + k];
    if (t < DZD) zi[t] = Z[i * DZD + t];
    __syncthreads();

    // full e^(2d) tables: each thread computes entries t and t+192
    #pragma unroll
    for (int rep = 0; rep < 2; ++rep) {
        const int a = t + rep * BLK;

        const float* __restrict__ xa = X + (size_t)a * DXD;
        float sq = 0.f;
        #pragma unroll
        for (int k = 0; k < DXD; k += 4) {
            float4 v = *reinterpret_cast<const float4*>(xa + k);
            float d0 = v.x - xi[k + 0], d1 = v.y - xi[k + 1];
            float d2 = v.z - xi[k + 2], d3 = v.w - xi[k + 3];
            sq += d0 * d0 + d1 * d1 + d2 * d2 + d3 * d3;
        }
        float dxv = (sq > 1e-12f) ? sqrtf(sq) : 0.f;
        ex[a] = __expf(TAU_INV * dxv);

        const float* __restrict__ za = Z + (size_t)a * DZD;
        float sqz = 0.f;
        #pragma unroll
        for (int k = 0; k < DZD; k += 4) {
            float4 v = *reinterpret_cast<const float4*>(za + k);
            float d0 = v.x - zi[k + 0], d1 = v.y - zi[k + 1];
            float d2 = v.z - zi[k + 2], d3 = v.w - zi[k + 3];
            sqz += d0 * d0 + d1 * d1 + d2 * d2 + d3 * d3;
        }
        float dzv = (sqz > 1e-12f) ? sqrtf(sqz) : 0.f;
        ez[a] = __expf(TAU_INV * dzv);
    }
    __syncthreads();

    // phase 2: b-loop over all 384, this thread's a = half*192 + t
    const int a = half * BLK + t;
    const float exa = ex[a];
    const float eza = ez[a];
    float sx0 = 0.f, sx1 = 0.f, sx2 = 0.f, sx3 = 0.f;
    float sz0 = 0.f, sz1 = 0.f, sz2 = 0.f, sz3 = 0.f;
    const float4* __restrict__ ex4 = reinterpret_cast<const float4*>(ex);
    const float4* __restrict__ ez4 = reinterpret_cast<const float4*>(ez);
    #pragma unroll 4
    for (int b = 0; b < N / 4; ++b) {
        float4 e = ex4[b];   // wave-uniform -> ds_read_b128 broadcast
        float4 f = ez4[b];
        sx0 += e.x * __builtin_amdgcn_rcpf(e.x + exa);
        sx1 += e.y * __builtin_amdgcn_rcpf(e.y + exa);
        sx2 += e.z * __builtin_amdgcn_rcpf(e.z + exa);
        sx3 += e.w * __builtin_amdgcn_rcpf(e.w + exa);
        sz0 += f.x * __builtin_amdgcn_rcpf(f.x + eza);
        sz1 += f.y * __builtin_amdgcn_rcpf(f.y + eza);
        sz2 += f.z * __builtin_amdgcn_rcpf(f.z + eza);
        sz3 += f.w * __builtin_amdgcn_rcpf(f.w + eza);
    }
    float sx = (sx0 + sx1) + (sx2 + sx3);
    float sz = (sz0 + sz1) + (sz2 + sz3);

    float intr = fmaxf(1.f + sx - KNEI, 0.f);
    float W = fminf(fmaxf((KNEI + 1.f - (1.f + sz)) * (1.f / KNEI), 0.f), 1.f);
    float contrib = intr * (1.f - W);

    #pragma unroll
    for (int off = 32; off > 0; off >>= 1)
        contrib += __shfl_down(contrib, off, 64);
    const int lane = t & 63, wid = t >> 6;
    if (lane == 0) red[wid] = contrib;
    __syncthreads();
    if (t == 0) {
        float s = 0.f;
        #pragma unroll
        for (int w = 0; w < BLK / 64; ++w) s += red[w];
        partial[blockIdx.x] = s;
    }
}

__global__ void __launch_bounds__(N) final_reduce(const float* __restrict__ partial,
                                                  float* __restrict__ out) {
    __shared__ float red[N / 64];
    float v = partial[threadIdx.x] + partial[threadIdx.x + N];
    #pragma unroll
    for (int off = 32; off > 0; off >>= 1)
        v += __shfl_down(v, off, 64);
    const int lane = threadIdx.x & 63, wid = threadIdx.x >> 6;
    if (lane == 0) red[wid] = v;
    __syncthreads();
    if (threadIdx.x == 0) {
        float s = 0.f;
        #pragma unroll
        for (int w = 0; w < N / 64; ++w) s += red[w];
        out[0] = s * NORM;
    }
}

extern "C" void kernel_launch(void* const* d_in, const int* in_sizes, int n_in,
                              void* d_out, int out_size, void* d_ws, size_t ws_size,
                              hipStream_t stream) {
    const float* X = (const float*)d_in[0];   // (384, 128) f32
    const float* Z = (const float*)d_in[1];   // (384, 32)  f32
    float* out = (float*)d_out;
    float* partial = (float*)d_ws;            // NBLK f32

    fused_loss<<<NBLK, BLK, 0, stream>>>(X, Z, partial);
    final_reduce<<<1, N, 0, stream>>>(partial, out);
}

// Round 3
// 39.627 us; speedup vs baseline: 1.2027x; 1.0629x over previous
//
#include <hip/hip_runtime.h>

#define N 384
#define DXD 128
#define DZD 32
#define NORM (2.0f / 1443840.0f)   // 2 / (n*K*(2n-3K-1)), n=384, K=5

// Kernel 1: E[i][j] = exp(2 * ||A_i - A_j||) for X (blocks 0..383) and Z
// (blocks 384..767). E is symmetric; rows written coalesced.
__global__ void __launch_bounds__(N) exp_rows(const float* __restrict__ X,
                                              const float* __restrict__ Z,
                                              float* __restrict__ EX,
                                              float* __restrict__ EZ) {
    __shared__ float rowi[DXD] __attribute__((aligned(16)));
    const int blk = blockIdx.x;
    const int t = threadIdx.x;
    if (blk < N) {
        const int i = blk;
        for (int k = t; k < DXD; k += N) rowi[k] = X[i * DXD + k];
        __syncthreads();
        const float* __restrict__ aj = X + (size_t)t * DXD;
        float sq = 0.f;
        #pragma unroll
        for (int k = 0; k < DXD; k += 4) {
            float4 v = *reinterpret_cast<const float4*>(aj + k);
            float d0 = v.x - rowi[k + 0], d1 = v.y - rowi[k + 1];
            float d2 = v.z - rowi[k + 2], d3 = v.w - rowi[k + 3];
            sq += d0 * d0 + d1 * d1 + d2 * d2 + d3 * d3;
        }
        float dist = (sq > 1e-12f) ? sqrtf(sq) : 0.f;
        EX[(size_t)i * N + t] = __expf(2.f * dist);
    } else {
        const int i = blk - N;
        if (t < DZD) rowi[t] = Z[i * DZD + t];
        __syncthreads();
        const float* __restrict__ aj = Z + (size_t)t * DZD;
        float sq = 0.f;
        #pragma unroll
        for (int k = 0; k < DZD; k += 4) {
            float4 v = *reinterpret_cast<const float4*>(aj + k);
            float d0 = v.x - rowi[k + 0], d1 = v.y - rowi[k + 1];
            float d2 = v.z - rowi[k + 2], d3 = v.w - rowi[k + 3];
            sq += d0 * d0 + d1 * d1 + d2 * d2 + d3 * d3;
        }
        float dist = (sq > 1e-12f) ? sqrtf(sq) : 0.f;
        EZ[(size_t)i * N + t] = __expf(2.f * dist);
    }
}

// Kernel 2: per (row i, 64-wide a-chunk) block; 2 waves split the b-range.
// sigmoid((d_b - d_a)/tau) = e_b / (e_b + e_a).
// e_b loads are wave-uniform -> scalar-cache / L1-broadcast, no LDS staging.
__global__ void __launch_bounds__(128) loss2(const float* __restrict__ EX,
                                             const float* __restrict__ EZ,
                                             float* __restrict__ partial) {
    __shared__ float sxs[64];
    __shared__ float szs[64];
    const int i = blockIdx.y;
    const int chunk = blockIdx.x;      // 0..5
    const int t = threadIdx.x;
    const int w = t >> 6, lane = t & 63;
    const int a = chunk * 64 + lane;

    const float* __restrict__ exrow = EX + (size_t)i * N;
    const float* __restrict__ ezrow = EZ + (size_t)i * N;
    const float exa = exrow[a];        // coalesced per-lane
    const float eza = ezrow[a];

    // wave w covers b in [w*192, w*192+192)
    const float4* __restrict__ ex4 = reinterpret_cast<const float4*>(exrow + w * (N / 2));
    const float4* __restrict__ ez4 = reinterpret_cast<const float4*>(ezrow + w * (N / 2));
    float sx0 = 0.f, sx1 = 0.f, sx2 = 0.f, sx3 = 0.f;
    float sz0 = 0.f, sz1 = 0.f, sz2 = 0.f, sz3 = 0.f;
    #pragma unroll 4
    for (int b = 0; b < N / 8; ++b) {      // 48 iters of 4 elements
        float4 e = ex4[b];                 // uniform address
        float4 f = ez4[b];
        sx0 += e.x * __builtin_amdgcn_rcpf(e.x + exa);
        sx1 += e.y * __builtin_amdgcn_rcpf(e.y + exa);
        sx2 += e.z * __builtin_amdgcn_rcpf(e.z + exa);
        sx3 += e.w * __builtin_amdgcn_rcpf(e.w + exa);
        sz0 += f.x * __builtin_amdgcn_rcpf(f.x + eza);
        sz1 += f.y * __builtin_amdgcn_rcpf(f.y + eza);
        sz2 += f.z * __builtin_amdgcn_rcpf(f.z + eza);
        sz3 += f.w * __builtin_amdgcn_rcpf(f.w + eza);
    }
    float sx = (sx0 + sx1) + (sx2 + sx3);
    float sz = (sz0 + sz1) + (sz2 + sz3);

    if (w == 1) { sxs[lane] = sx; szs[lane] = sz; }
    __syncthreads();
    if (w == 0) {
        sx += sxs[lane];
        sz += szs[lane];
        // intrusion = relu(1 + sx - K); W = clamp((K+1-(1+sz))/K, 0, 1)
        float intr = fmaxf(sx - 4.f, 0.f);
        float W = fminf(fmaxf((5.f - sz) * 0.2f, 0.f), 1.f);
        float contrib = intr * (1.f - W);
        #pragma unroll
        for (int off = 32; off > 0; off >>= 1)
            contrib += __shfl_down(contrib, off, 64);
        if (lane == 0) partial[i * 6 + chunk] = contrib;
    }
}

// Kernel 3: sum 2304 partials * NORM
__global__ void __launch_bounds__(256) final_reduce(const float* __restrict__ partial,
                                                    float* __restrict__ out) {
    __shared__ float red[4];
    const int t = threadIdx.x;
    float v = 0.f;
    #pragma unroll
    for (int k = 0; k < 9; ++k) v += partial[t + k * 256];
    #pragma unroll
    for (int off = 32; off > 0; off >>= 1)
        v += __shfl_down(v, off, 64);
    const int lane = t & 63, wid = t >> 6;
    if (lane == 0) red[wid] = v;
    __syncthreads();
    if (t == 0) {
        float s = (red[0] + red[1]) + (red[2] + red[3]);
        out[0] = s * NORM;
    }
}

extern "C" void kernel_launch(void* const* d_in, const int* in_sizes, int n_in,
                              void* d_out, int out_size, void* d_ws, size_t ws_size,
                              hipStream_t stream) {
    const float* X = (const float*)d_in[0];   // (384, 128) f32
    const float* Z = (const float*)d_in[1];   // (384, 32)  f32
    float* out = (float*)d_out;

    float* EX = (float*)d_ws;                  // N*N f32
    float* EZ = EX + (size_t)N * N;            // N*N f32
    float* partial = EZ + (size_t)N * N;       // 2304 f32

    exp_rows<<<2 * N, N, 0, stream>>>(X, Z, EX, EZ);
    loss2<<<dim3(6, N), 128, 0, stream>>>(EX, EZ, partial);
    final_reduce<<<1, 256, 0, stream>>>(partial, out);
}